// Round 13
// baseline (2016.734 us; speedup 1.0000x reference)
//
#include <hip/hip_runtime.h>
#include <cmath>

typedef __attribute__((ext_vector_type(8))) short bf16x8;
typedef __attribute__((ext_vector_type(8))) ushort u16x8;
typedef __attribute__((ext_vector_type(4))) ushort u16x4;
typedef __attribute__((ext_vector_type(4))) uint u32x4;
typedef __attribute__((ext_vector_type(4))) float f32x4;

static constexpr int Bn = 64, Tn = 512, Fn = 784, Hn = 512, G4n = 2048, On = 10;
static constexpr int NBLK = 64;
static constexpr int KP = 800;                             // 784 padded to 25*32
static constexpr long XZ_ELEMS   = (long)Bn * Tn * G4n;    // 256 MB
static constexpr long HSEQ_ELEMS = (long)Bn * Tn * Hn;     // 64 MB
// hfrag: 2 parity x 4 cluster x 8192 tagged uints = 65536 uints (256 KB)
static constexpr size_t BASE_END = (size_t)XZ_ELEMS * 4 + (size_t)HSEQ_ELEMS * 4
                                 + (size_t)65536 * 4;               // 335,806,464
static constexpr size_t MFMA_END = BASE_END + (size_t)32768 * KP * 2
                                 + 2 * (size_t)G4n * KP * 2;        // 394,788,864

__device__ __forceinline__ ushort f2bf(float x) {   // RNE fp32->bf16
  uint b = __float_as_uint(x);
  uint r = (b + 0x7FFFu + ((b >> 16) & 1u)) >> 16;
  return (ushort)r;
}
__device__ __forceinline__ float bf2f(ushort h) {
  return __uint_as_float(((uint)h) << 16);
}
__device__ __forceinline__ float sigf(float x)  { return 1.f / (1.f + __expf(-x)); }
__device__ __forceinline__ float tanhff(float x) { return 1.f - 2.f / (__expf(2.f * x) + 1.f); }

// ---------------- P1: x [32768][784] f32 -> xhi/xlo [32768][800] bf16 ----------------
__global__ __launch_bounds__(256) void cvt_x(
    const float* __restrict__ x, ushort* __restrict__ xhi, ushort* __restrict__ xlo)
{
  const int idx = blockIdx.x * 256 + threadIdx.x;   // 32768*100
  const int m = idx / 100, kc = idx - m * 100;
  u16x8 h = {0,0,0,0,0,0,0,0}, lo = {0,0,0,0,0,0,0,0};
  if (kc < 98) {   // 784 = 98*8 exactly
    const float4 v0 = *(const float4*)(x + (size_t)m * Fn + kc * 8);
    const float4 v1 = *(const float4*)(x + (size_t)m * Fn + kc * 8 + 4);
    const float vv[8] = {v0.x, v0.y, v0.z, v0.w, v1.x, v1.y, v1.z, v1.w};
#pragma unroll
    for (int e = 0; e < 8; ++e) {
      const ushort hh = f2bf(vv[e]);
      h[e] = hh;
      lo[e] = f2bf(vv[e] - bf2f(hh));
    }
  }
  *(u16x8*)(xhi + (size_t)m * KP + kc * 8) = h;
  *(u16x8*)(xlo + (size_t)m * KP + kc * 8) = lo;
}

// ---------------- P2: W [784][2048] f32 -> WThi/WTlo [2048][800] bf16 ----------------
__global__ __launch_bounds__(256) void cvt_w(
    const float* __restrict__ W, ushort* __restrict__ WThi, ushort* __restrict__ WTlo)
{
  const int idx = blockIdx.x * 256 + threadIdx.x;   // 100*2048
  const int kc = idx >> 11, gcol = idx & 2047;
  u16x8 h = {0,0,0,0,0,0,0,0}, lo = {0,0,0,0,0,0,0,0};
#pragma unroll
  for (int e = 0; e < 8; ++e) {
    const int k = kc * 8 + e;
    if (k < Fn) {
      const float v = W[(size_t)k * G4n + gcol];
      const ushort hh = f2bf(v);
      h[e] = hh;
      lo[e] = f2bf(v - bf2f(hh));
    }
  }
  *(u16x8*)(WThi + (size_t)gcol * KP + kc * 8) = h;
  *(u16x8*)(WTlo + (size_t)gcol * KP + kc * 8) = lo;
}

// ---------------- K1: xzT[t][gcol][beta] = (x@W+b)^T via MFMA (R9, proven) ----------
__global__ __launch_bounds__(256, 2) void gemm_xz_mfma(
    const ushort* __restrict__ WThi, const ushort* __restrict__ WTlo,
    const ushort* __restrict__ xhi,  const ushort* __restrict__ xlo,
    const float* __restrict__ bias, float* __restrict__ xzT)
{
  const int tid = threadIdx.x;
  const int wv = tid >> 6, l = tid & 63;
  const int wr = wv >> 1, wc = wv & 1;
  const int gt  = blockIdx.x & 15;
  const int bgh = (blockIdx.x >> 4) & 1;
  const int t0  = blockIdx.x >> 5;
  const int g0 = gt * 128 + wr * 64;
  const int bg0 = bgh * 32 + wc * 16;
  const int t_base = t0 * 4;
  const int n = l & 15, kg = l >> 4;

  const ushort* pah = WThi + (size_t)(g0 + n) * KP + kg * 8;
  const ushort* pal = WTlo + (size_t)(g0 + n) * KP + kg * 8;
  const size_t mrow = ((size_t)(bg0 + n) * Tn + t_base) * KP + kg * 8;
  const ushort* pbh = xhi + mrow;
  const ushort* pbl = xlo + mrow;

  f32x4 acc[4][4] = {};
  for (int ks = 0; ks < 25; ++ks) {
    bf16x8 ah[4], al[4], bh[4], bl[4];
#pragma unroll
    for (int i = 0; i < 4; ++i) {
      const size_t ao = (size_t)i * 16 * KP + ks * 32;
      ah[i] = *(const bf16x8*)(pah + ao);
      al[i] = *(const bf16x8*)(pal + ao);
      const size_t bo = (size_t)i * KP + ks * 32;
      bh[i] = *(const bf16x8*)(pbh + bo);
      bl[i] = *(const bf16x8*)(pbl + bo);
    }
#pragma unroll
    for (int ai = 0; ai < 4; ++ai)
#pragma unroll
      for (int bj = 0; bj < 4; ++bj) {
        acc[ai][bj] = __builtin_amdgcn_mfma_f32_16x16x32_bf16(ah[ai], bh[bj], acc[ai][bj], 0, 0, 0);
        acc[ai][bj] = __builtin_amdgcn_mfma_f32_16x16x32_bf16(ah[ai], bl[bj], acc[ai][bj], 0, 0, 0);
        acc[ai][bj] = __builtin_amdgcn_mfma_f32_16x16x32_bf16(al[ai], bh[bj], acc[ai][bj], 0, 0, 0);
      }
  }
#pragma unroll
  for (int ai = 0; ai < 4; ++ai) {
#pragma unroll
    for (int r = 0; r < 4; ++r) {
      const int gc = g0 + ai * 16 + (kg << 2) + r;
      const float bb = bias[gc];
#pragma unroll
      for (int bj = 0; bj < 4; ++bj)
        xzT[((size_t)(t_base + bj) * G4n + gc) * Bn + bg0 + n] = acc[ai][bj][r] + bb;
    }
  }
}

// ---------------- K1-fallback: fp32 tiled ----------------
__global__ __launch_bounds__(256) void gemm_xz_f32(
    const float* __restrict__ A, const float* __restrict__ W,
    const float* __restrict__ bias, float* __restrict__ xzT)
{
  __shared__ float As[16][68];
  __shared__ float Bs[16][68];
  const int tid = threadIdx.x;
  const int tx = tid & 15, ty = tid >> 4;
  const int g0 = blockIdx.x * 64;
  const int tt = blockIdx.y;
  const int ar = tid >> 2, ac = (tid & 3) << 2;
  const int br = tid >> 4, bc = (tid & 15) << 2;
  float acc[4][4] = {};
  for (int kt = 0; kt < Fn; kt += 16) {
    const float4 a4 = *(const float4*)(A + ((size_t)ar * Tn + tt) * Fn + kt + ac);
    const float4 b4 = *(const float4*)(W + (size_t)(kt + br) * G4n + g0 + bc);
    __syncthreads();
    As[ac + 0][ar] = a4.x; As[ac + 1][ar] = a4.y;
    As[ac + 2][ar] = a4.z; As[ac + 3][ar] = a4.w;
    *(float4*)(&Bs[br][bc]) = b4;
    __syncthreads();
#pragma unroll
    for (int k = 0; k < 16; ++k) {
      const float4 av = *(const float4*)(&As[k][ty << 2]);
      const float4 bv = *(const float4*)(&Bs[k][tx << 2]);
      const float aarr[4] = {av.x, av.y, av.z, av.w};
      const float barr[4] = {bv.x, bv.y, bv.z, bv.w};
#pragma unroll
      for (int i = 0; i < 4; ++i)
#pragma unroll
        for (int j = 0; j < 4; ++j)
          acc[i][j] = fmaf(aarr[i], barr[j], acc[i][j]);
    }
  }
#pragma unroll
  for (int j = 0; j < 4; ++j) {
    const int gcol = g0 + (tx << 2) + j;
    const float bb = bias[gcol];
    float4 ov;
    ov.x = acc[0][j] + bb;
    ov.y = acc[1][j] + bb;
    ov.z = acc[2][j] + bb;
    ov.w = acc[3][j] + bb;
    *(float4*)(xzT + ((size_t)tt * G4n + gcol) * Bn + (ty << 2)) = ov;
  }
}

// ---------------- K2: MFMA LSTM, coalesced exchange commit ----------------
// R12 structure + poll; ONLY change: the exchange write. A block's 512 tagged
// dwords form the contiguous region [s*512, s*512+512) of its cluster buffer
// (slot = s*512 + sub*128 + n*8 + j8). Gather them into a 2 KB LDS buffer
// (bijective thread->loc), sync, then lanes 0..127 emit 128 dwordx4 sc0 sc1
// stores = 32 full 64B lines, write-combined -> fast L3 commit (vs 512
// scattered cross-wave dwords in R12, the suspected 2us/step commit cost).
// Exchange stores issued BEFORE the h_seq scatter so they are oldest in queue.
__global__ __launch_bounds__(512) void lstm_mfma(
    const float* __restrict__ xzT, const float* __restrict__ U,
    float* __restrict__ h_seq, uint* __restrict__ hfrag_u)
{
  __shared__ ushort hsm[8192];     // 16 KB: cluster h (bf16) in B-frag layout
  __shared__ uint lsm[512];        // 2 KB: outgoing tagged dwords, slot-ordered
  const int tid = threadIdx.x;
  const int blk = blockIdx.x;      // 0..63
  const int w = tid >> 6, l = tid & 63;
  const int n = l & 15, kg = l >> 4;
  const int mt = blk >> 4;         // cluster
  const int s  = blk & 15;         // hcol slice
  const int hc0 = (s << 5) + (w << 2);

  // ---- one-time: U^T A-fragments (bf16 hi+lo split) ----
  const int ugcol = ((n & 3) << 9) + hc0 + (n >> 2);
  bf16x8 ufhi[16], uflo[16];
#pragma unroll
  for (int ks = 0; ks < 16; ++ks) {
    bf16x8 hi, lo;
#pragma unroll
    for (int e = 0; e < 8; ++e) {
      const float u = U[(size_t)(32 * ks + 8 * kg + e) * G4n + ugcol];
      const ushort uh = f2bf(u);
      hi[e] = (short)uh;
      lo[e] = (short)f2bf(u - bf2f(uh));
    }
    ufhi[ks] = hi; uflo[ks] = lo;
  }

  const int beta = (mt << 4) + n;       // batch this lane owns
  const int hc   = hc0 + kg;            // h-col this lane owns
  float cst = 0.f;

  // local gather index: loc = slot - s*512 = sub*128 + n*8 + j8 (bijective in tid)
  const int sub = ((w << 2) + kg) >> 3;
  const int j8  = ((w << 2) + kg) & 7;
  const int loc = sub * 128 + n * 8 + j8;
  const uint cbase = (uint)mt * 8192u;

  float xzc[4];
#pragma unroll
  for (int r = 0; r < 4; ++r)
    xzc[r] = xzT[((size_t)(r << 9) + hc) * Bn + beta];   // t = 0

  for (int t = 0; t < Tn; ++t) {
    const uint rbuf = ((uint)t & 1u) * 32768u + cbase;
    const uint wbuf = ((uint)(t + 1) & 1u) * 32768u + cbase;
    const uint want = (uint)t;

    // prefetch next xz early (independent; overlaps the poll)
    float xzn[4];
    if (t + 1 < Tn) {
#pragma unroll
      for (int r = 0; r < 4; ++r)
        xzn[r] = xzT[((size_t)(t + 1) * G4n + (r << 9) + hc) * Bn + beta];
    } else {
#pragma unroll
      for (int r = 0; r < 4; ++r) xzn[r] = 0.f;
    }

    // ---- poll: 4 x dwordx4 batched, ONE vmcnt wait per round ----
    const uint* pr0 = hfrag_u + rbuf + (tid << 2);
    u32x4 v0, v1, v2, v3;
    while (true) {
      asm volatile(
        "global_load_dwordx4 %0, %4, off sc0 sc1\n\t"
        "global_load_dwordx4 %1, %5, off sc0 sc1\n\t"
        "global_load_dwordx4 %2, %6, off sc0 sc1\n\t"
        "global_load_dwordx4 %3, %7, off sc0 sc1\n\t"
        "s_waitcnt vmcnt(0)"
        : "=&v"(v0), "=&v"(v1), "=&v"(v2), "=&v"(v3)
        : "v"(pr0), "v"(pr0 + 2048), "v"(pr0 + 4096), "v"(pr0 + 6144)
        : "memory");
      const bool ok =
          (v0[0] >> 16) == want && (v0[1] >> 16) == want &&
          (v0[2] >> 16) == want && (v0[3] >> 16) == want &&
          (v1[0] >> 16) == want && (v1[1] >> 16) == want &&
          (v1[2] >> 16) == want && (v1[3] >> 16) == want &&
          (v2[0] >> 16) == want && (v2[1] >> 16) == want &&
          (v2[2] >> 16) == want && (v2[3] >> 16) == want &&
          (v3[0] >> 16) == want && (v3[1] >> 16) == want &&
          (v3[2] >> 16) == want && (v3[3] >> 16) == want;
      if (ok) break;
    }
    {
      u16x4 s0 = {(ushort)v0[0], (ushort)v0[1], (ushort)v0[2], (ushort)v0[3]};
      u16x4 s1 = {(ushort)v1[0], (ushort)v1[1], (ushort)v1[2], (ushort)v1[3]};
      u16x4 s2 = {(ushort)v2[0], (ushort)v2[1], (ushort)v2[2], (ushort)v2[3]};
      u16x4 s3 = {(ushort)v3[0], (ushort)v3[1], (ushort)v3[2], (ushort)v3[3]};
      *(u16x4*)(hsm + (tid << 2))        = s0;
      *(u16x4*)(hsm + (tid << 2) + 2048) = s1;
      *(u16x4*)(hsm + (tid << 2) + 4096) = s2;
      *(u16x4*)(hsm + (tid << 2) + 6144) = s3;
    }
    __syncthreads();                    // stage complete

    // ---- MFMA: z^T = U^T (A, regs) x h^T (B, LDS) ----
    const bf16x8* bb = ((const bf16x8*)hsm) + l;
    f32x4 acch = {0.f, 0.f, 0.f, 0.f};
    f32x4 accl = {0.f, 0.f, 0.f, 0.f};
#pragma unroll
    for (int ks = 0; ks < 16; ++ks) {
      const bf16x8 bfr = bb[ks * 64];
      acch = __builtin_amdgcn_mfma_f32_16x16x32_bf16(ufhi[ks], bfr, acch, 0, 0, 0);
      accl = __builtin_amdgcn_mfma_f32_16x16x32_bf16(uflo[ks], bfr, accl, 0, 0, 0);
    }

    // reg r = gate r (Keras i,f,g,o) for (batch beta, hcol hc)
    const float zi = acch[0] + accl[0] + xzc[0];
    const float zf = acch[1] + accl[1] + xzc[1];
    const float zg = acch[2] + accl[2] + xzc[2];
    const float zo = acch[3] + accl[3] + xzc[3];
    const float iv = sigf(zi), fv = sigf(zf), gv = tanhff(zg), ov = sigf(zo);
    cst = fv * cst + iv * gv;
    const float hv = ov * tanhff(cst);

    // gather outgoing tagged word into LDS (slot-ordered)
    lsm[loc] = (((uint)(t + 1)) << 16) | (uint)f2bf(hv);
    __syncthreads();                    // lsm complete; also fences hsm reads

    // ---- coalesced exchange commit: 128 lanes x dwordx4 sc0 sc1 ----
    if (tid < 128) {
      const u32x4 ov4 = *(const u32x4*)(lsm + (tid << 2));
      uint* wp = hfrag_u + wbuf + ((uint)s << 9) + (tid << 2);
      asm volatile("global_store_dwordx4 %0, %1, off sc0 sc1"
                   :: "v"(wp), "v"(ov4) : "memory");
    }
    // h_seq scatter (off critical path, issued after exchange)
    h_seq[((size_t)beta * Tn + t) * Hn + hc] = hv;

#pragma unroll
    for (int r = 0; r < 4; ++r) xzc[r] = xzn[r];
  }
}

// ---------------- K3: out = h_seq @ Wd + bd ----------------
__global__ __launch_bounds__(256) void proj_out(
    const float* __restrict__ h_seq, const float* __restrict__ Wd,
    const float* __restrict__ bd, float* __restrict__ out)
{
  __shared__ float Wdt[10][516];
  for (int i = threadIdx.x; i < Hn * On; i += 256) {
    const int k = i / 10, o = i - k * 10;
    Wdt[o][k] = Wd[i];
  }
  __syncthreads();
  const int idx = blockIdx.x * 256 + threadIdx.x;
  const int row = idx / 10, o = idx - row * 10;
  const float* hp = h_seq + (size_t)row * Hn;
  const float* wp = &Wdt[o][0];
  float acc = bd[o];
#pragma unroll 4
  for (int k = 0; k < Hn; k += 4) {
    const float4 h4 = *(const float4*)(hp + k);
    const float4 w4 = *(const float4*)(wp + k);
    acc = fmaf(h4.x, w4.x, acc);
    acc = fmaf(h4.y, w4.y, acc);
    acc = fmaf(h4.z, w4.z, acc);
    acc = fmaf(h4.w, w4.w, acc);
  }
  out[idx] = acc;
}

extern "C" void kernel_launch(void* const* d_in, const int* in_sizes, int n_in,
                              void* d_out, int out_size, void* d_ws, size_t ws_size,
                              hipStream_t stream)
{
  const float* x  = (const float*)d_in[0];
  const float* W  = (const float*)d_in[1];
  const float* U  = (const float*)d_in[2];
  const float* b  = (const float*)d_in[3];
  const float* Wd = (const float*)d_in[4];
  const float* bd = (const float*)d_in[5];
  float* out = (float*)d_out;

  float* xzT    = (float*)d_ws;
  float* h_seq  = xzT + XZ_ELEMS;
  uint* hfrag_u = (uint*)(h_seq + HSEQ_ELEMS);      // 65536 tagged uints
  ushort* xhi  = (ushort*)h_seq;                    // overlap: dead until lstm
  ushort* xlo  = (ushort*)((char*)d_ws + BASE_END);
  ushort* WThi = xlo + (size_t)32768 * KP;
  ushort* WTlo = WThi + (size_t)G4n * KP;

  if (ws_size >= MFMA_END) {
    cvt_x<<<12800, 256, 0, stream>>>(x, xhi, xlo);
    cvt_w<<<800, 256, 0, stream>>>(W, WThi, WTlo);
    gemm_xz_mfma<<<4096, 256, 0, stream>>>(WThi, WTlo, xhi, xlo, b, xzT);
  } else {
    gemm_xz_f32<<<dim3(G4n / 64, Tn), 256, 0, stream>>>(x, W, b, xzT);
  }

  hipMemsetAsync(hfrag_u, 0, 65536 * sizeof(uint), stream);   // tags=0 -> h_{-1}=0
  lstm_mfma<<<dim3(NBLK), dim3(512), 0, stream>>>(xzT, U, h_seq, hfrag_u);

  proj_out<<<(Bn * Tn * On) / 256, 256, 0, stream>>>(h_seq, Wd, bd, out);
}

// Round 14
// 1278.734 us; speedup vs baseline: 1.5771x; 1.5771x over previous
//
#include <hip/hip_runtime.h>
#include <cmath>

typedef __attribute__((ext_vector_type(8))) short bf16x8;
typedef __attribute__((ext_vector_type(8))) ushort u16x8;
typedef __attribute__((ext_vector_type(4))) ushort u16x4;
typedef __attribute__((ext_vector_type(4))) uint u32x4;
typedef __attribute__((ext_vector_type(4))) float f32x4;

static constexpr int Bn = 64, Tn = 512, Fn = 784, Hn = 512, G4n = 2048, On = 10;
static constexpr int KP = 800;                             // 784 padded to 25*32
static constexpr long XZ_ELEMS   = (long)Bn * Tn * G4n;    // 256 MB fp32
static constexpr long HSEQ_ELEMS = (long)Bn * Tn * Hn;     // bf16 now: 32 MB

__device__ __forceinline__ ushort f2bf(float x) {   // RNE fp32->bf16
  uint b = __float_as_uint(x);
  uint r = (b + 0x7FFFu + ((b >> 16) & 1u)) >> 16;
  return (ushort)r;
}
__device__ __forceinline__ float bf2f(ushort h) {
  return __uint_as_float(((uint)h) << 16);
}
__device__ __forceinline__ float sigf(float x)  { return 1.f / (1.f + __expf(-x)); }
__device__ __forceinline__ float tanhff(float x) { return 1.f - 2.f / (__expf(2.f * x) + 1.f); }

// ---------------- P1: x [32768][784] f32 -> xhi [32768][800] bf16 (single) ----------------
__global__ __launch_bounds__(256) void cvt_x(
    const float* __restrict__ x, ushort* __restrict__ xhi)
{
  const int idx = blockIdx.x * 256 + threadIdx.x;   // 32768*100
  const int m = idx / 100, kc = idx - m * 100;
  u16x8 h = {0,0,0,0,0,0,0,0};
  if (kc < 98) {   // 784 = 98*8 exactly
    const float4 v0 = *(const float4*)(x + (size_t)m * Fn + kc * 8);
    const float4 v1 = *(const float4*)(x + (size_t)m * Fn + kc * 8 + 4);
    const float vv[8] = {v0.x, v0.y, v0.z, v0.w, v1.x, v1.y, v1.z, v1.w};
#pragma unroll
    for (int e = 0; e < 8; ++e) h[e] = f2bf(vv[e]);
  }
  *(u16x8*)(xhi + (size_t)m * KP + kc * 8) = h;
}

// ---------------- P2: W [784][2048] f32 -> WThi/WTlo [2048][800] bf16 ----------------
__global__ __launch_bounds__(256) void cvt_w(
    const float* __restrict__ W, ushort* __restrict__ WThi, ushort* __restrict__ WTlo)
{
  const int idx = blockIdx.x * 256 + threadIdx.x;   // 100*2048
  const int kc = idx >> 11, gcol = idx & 2047;
  u16x8 h = {0,0,0,0,0,0,0,0}, lo = {0,0,0,0,0,0,0,0};
#pragma unroll
  for (int e = 0; e < 8; ++e) {
    const int k = kc * 8 + e;
    if (k < Fn) {
      const float v = W[(size_t)k * G4n + gcol];
      const ushort hh = f2bf(v);
      h[e] = hh;
      lo[e] = f2bf(v - bf2f(hh));
    }
  }
  *(u16x8*)(WThi + (size_t)gcol * KP + kc * 8) = h;
  *(u16x8*)(WTlo + (size_t)gcol * KP + kc * 8) = lo;
}

// ---------------- K1-fallback: fp32 tiled xzT (stream-ordered, pre-fused) ----------------
__global__ __launch_bounds__(256) void gemm_xz_f32(
    const float* __restrict__ A, const float* __restrict__ W,
    const float* __restrict__ bias, float* __restrict__ xzT)
{
  __shared__ float As[16][68];
  __shared__ float Bs[16][68];
  const int tid = threadIdx.x;
  const int tx = tid & 15, ty = tid >> 4;
  const int g0 = blockIdx.x * 64;
  const int tt = blockIdx.y;
  const int ar = tid >> 2, ac = (tid & 3) << 2;
  const int br = tid >> 4, bc = (tid & 15) << 2;
  float acc[4][4] = {};
  for (int kt = 0; kt < Fn; kt += 16) {
    const float4 a4 = *(const float4*)(A + ((size_t)ar * Tn + tt) * Fn + kt + ac);
    const float4 b4 = *(const float4*)(W + (size_t)(kt + br) * G4n + g0 + bc);
    __syncthreads();
    As[ac + 0][ar] = a4.x; As[ac + 1][ar] = a4.y;
    As[ac + 2][ar] = a4.z; As[ac + 3][ar] = a4.w;
    *(float4*)(&Bs[br][bc]) = b4;
    __syncthreads();
#pragma unroll
    for (int k = 0; k < 16; ++k) {
      const float4 av = *(const float4*)(&As[k][ty << 2]);
      const float4 bv = *(const float4*)(&Bs[k][tx << 2]);
      const float aarr[4] = {av.x, av.y, av.z, av.w};
      const float barr[4] = {bv.x, bv.y, bv.z, bv.w};
#pragma unroll
      for (int i = 0; i < 4; ++i)
#pragma unroll
        for (int j = 0; j < 4; ++j)
          acc[i][j] = fmaf(aarr[i], barr[j], acc[i][j]);
    }
  }
#pragma unroll
  for (int j = 0; j < 4; ++j) {
    const int gcol = g0 + (tx << 2) + j;
    const float bb = bias[gcol];
    float4 ov;
    ov.x = acc[0][j] + bb;
    ov.y = acc[1][j] + bb;
    ov.z = acc[2][j] + bb;
    ov.w = acc[3][j] + bb;
    *(float4*)(xzT + ((size_t)tt * G4n + gcol) * Bn + (ty << 2)) = ov;
  }
}

__global__ void fill_cnt(uint* cnt) { if (threadIdx.x < 128) cnt[threadIdx.x] = 16u; }

// ---------------- FUSED: producer GEMM (blocks 64..255) + LSTM recurrence (0..63) --------
// Producers: persistent sweep of 2048 tiles (t0 ascending; 16 gt-blocks per t0
// group of 4 t's). Per tile: 2-term bf16 MFMA (Whi*x + Wlo*x), epilogue via
// sc0 sc1 write-through stores, vmcnt(0)+syncthreads, one device atomicAdd on
// cnt[t0]. Recurrence: R13 body; xz reads via sc0 sc1 asm loads gated by
// cnt[(t+1)>>2]==16 once per 4 steps. 256 blocks <= 256 CUs -> all co-resident.
__global__ __launch_bounds__(512) void fused_lstm(
    float* __restrict__ xzT, const float* __restrict__ U,
    ushort* __restrict__ h_seq, uint* __restrict__ hfrag_u, uint* __restrict__ cnt,
    const ushort* __restrict__ WThi, const ushort* __restrict__ WTlo,
    const ushort* __restrict__ xhi, const float* __restrict__ bias, int do_gemm)
{
  __shared__ ushort hsm[8192];     // 16 KB (recurrence)
  __shared__ uint lsm[512];        // 2 KB (recurrence)
  const int tid = threadIdx.x;

  if (blockIdx.x >= 64) {
    // ================= producer GEMM =================
    if (!do_gemm) return;
    const int p = blockIdx.x - 64;          // 0..191
    const int wv = tid >> 6, l = tid & 63;
    const int bgh = wv >> 2, wr = (wv >> 1) & 1, wc = wv & 1;
    const int n = l & 15, kg = l >> 4;
    for (int tile = p; tile < 2048; tile += 192) {
      const int t0 = tile >> 4, gt = tile & 15;
      const int g0 = gt * 128 + wr * 64;
      const int bg0 = bgh * 32 + wc * 16;
      const int t_base = t0 * 4;
      const ushort* pah = WThi + (size_t)(g0 + n) * KP + kg * 8;
      const ushort* pal = WTlo + (size_t)(g0 + n) * KP + kg * 8;
      const ushort* pbh = xhi + ((size_t)(bg0 + n) * Tn + t_base) * KP + kg * 8;
      f32x4 acc[4][4] = {};
      for (int ks = 0; ks < 25; ++ks) {
        bf16x8 ah[4], al[4], bh[4];
#pragma unroll
        for (int i = 0; i < 4; ++i) {
          const size_t ao = (size_t)i * 16 * KP + ks * 32;
          ah[i] = *(const bf16x8*)(pah + ao);
          al[i] = *(const bf16x8*)(pal + ao);
          bh[i] = *(const bf16x8*)(pbh + (size_t)i * KP + ks * 32);
        }
#pragma unroll
        for (int ai = 0; ai < 4; ++ai)
#pragma unroll
          for (int bj = 0; bj < 4; ++bj) {
            acc[ai][bj] = __builtin_amdgcn_mfma_f32_16x16x32_bf16(ah[ai], bh[bj], acc[ai][bj], 0, 0, 0);
            acc[ai][bj] = __builtin_amdgcn_mfma_f32_16x16x32_bf16(al[ai], bh[bj], acc[ai][bj], 0, 0, 0);
          }
      }
#pragma unroll
      for (int ai = 0; ai < 4; ++ai) {
#pragma unroll
        for (int r = 0; r < 4; ++r) {
          const int gc = g0 + ai * 16 + (kg << 2) + r;
          const float bb = bias[gc];
#pragma unroll
          for (int bj = 0; bj < 4; ++bj) {
            float* wp = xzT + ((size_t)(t_base + bj) * G4n + gc) * Bn + bg0 + n;
            const float v = acc[ai][bj][r] + bb;
            asm volatile("global_store_dword %0, %1, off sc0 sc1"
                         :: "v"(wp), "v"(v) : "memory");
          }
        }
      }
      asm volatile("s_waitcnt vmcnt(0)" ::: "memory");
      __syncthreads();                        // all waves' stores committed
      if (tid == 0) atomicAdd(&cnt[t0], 1u);  // device-scope release of this tile
    }
    return;
  }

  // ================= LSTM recurrence (R13 body; xz via sc1+counters) =================
  const int blk = blockIdx.x;      // 0..63
  const int w = tid >> 6, l = tid & 63;
  const int n = l & 15, kg = l >> 4;
  const int mt = blk >> 4;         // cluster
  const int s  = blk & 15;         // hcol slice
  const int hc0 = (s << 5) + (w << 2);

  const int ugcol = ((n & 3) << 9) + hc0 + (n >> 2);
  bf16x8 ufhi[16], uflo[16];
#pragma unroll
  for (int ks = 0; ks < 16; ++ks) {
    bf16x8 hi, lo;
#pragma unroll
    for (int e = 0; e < 8; ++e) {
      const float u = U[(size_t)(32 * ks + 8 * kg + e) * G4n + ugcol];
      const ushort uh = f2bf(u);
      hi[e] = (short)uh;
      lo[e] = (short)f2bf(u - bf2f(uh));
    }
    ufhi[ks] = hi; uflo[ks] = lo;
  }

  const int beta = (mt << 4) + n;
  const int hc   = hc0 + kg;
  float cst = 0.f;

  const int sub = ((w << 2) + kg) >> 3;
  const int j8  = ((w << 2) + kg) & 7;
  const int loc = sub * 128 + n * 8 + j8;
  const uint cbase = (uint)mt * 8192u;
  const float* xz0 = xzT + (size_t)hc * Bn + beta;

  // wait for t-group 0, then issue t=0 xz loads (drained by first poll)
  if (tid == 0) {
    while (__hip_atomic_load(&cnt[0], __ATOMIC_RELAXED, __HIP_MEMORY_SCOPE_AGENT) < 16u)
      __builtin_amdgcn_s_sleep(2);
  }
  __syncthreads();
  float xzc[4];
#pragma unroll
  for (int r = 0; r < 4; ++r) {
    const float* p0 = xz0 + (size_t)(r << 9) * Bn;
    asm volatile("global_load_dword %0, %1, off sc0 sc1"
                 : "=v"(xzc[r]) : "v"(p0) : "memory");
  }

  for (int t = 0; t < Tn; ++t) {
    const uint rbuf = ((uint)t & 1u) * 32768u + cbase;
    const uint wbuf = ((uint)(t + 1) & 1u) * 32768u + cbase;
    const uint want = (uint)t;

    // gate on producer counter once per 4 steps
    if (t + 1 < Tn && ((t + 1) & 3) == 0) {
      const uint g = (uint)(t + 1) >> 2;
      if (tid == 0) {
        while (__hip_atomic_load(&cnt[g], __ATOMIC_RELAXED, __HIP_MEMORY_SCOPE_AGENT) < 16u)
          __builtin_amdgcn_s_sleep(2);
      }
      __syncthreads();
    }
    // prefetch next xz (sc1; drained by the poll's vmcnt(0))
    float xzn[4] = {0.f, 0.f, 0.f, 0.f};
    if (t + 1 < Tn) {
#pragma unroll
      for (int r = 0; r < 4; ++r) {
        const float* p0 = xz0 + ((size_t)(t + 1) * G4n + (r << 9)) * Bn;
        asm volatile("global_load_dword %0, %1, off sc0 sc1"
                     : "=v"(xzn[r]) : "v"(p0) : "memory");
      }
    }

    // ---- poll: 4 x dwordx4 batched, ONE vmcnt wait per round ----
    const uint* pr0 = hfrag_u + rbuf + (tid << 2);
    u32x4 v0, v1, v2, v3;
    while (true) {
      asm volatile(
        "global_load_dwordx4 %0, %4, off sc0 sc1\n\t"
        "global_load_dwordx4 %1, %5, off sc0 sc1\n\t"
        "global_load_dwordx4 %2, %6, off sc0 sc1\n\t"
        "global_load_dwordx4 %3, %7, off sc0 sc1\n\t"
        "s_waitcnt vmcnt(0)"
        : "=&v"(v0), "=&v"(v1), "=&v"(v2), "=&v"(v3)
        : "v"(pr0), "v"(pr0 + 2048), "v"(pr0 + 4096), "v"(pr0 + 6144)
        : "memory");
      const bool ok =
          (v0[0] >> 16) == want && (v0[1] >> 16) == want &&
          (v0[2] >> 16) == want && (v0[3] >> 16) == want &&
          (v1[0] >> 16) == want && (v1[1] >> 16) == want &&
          (v1[2] >> 16) == want && (v1[3] >> 16) == want &&
          (v2[0] >> 16) == want && (v2[1] >> 16) == want &&
          (v2[2] >> 16) == want && (v2[3] >> 16) == want &&
          (v3[0] >> 16) == want && (v3[1] >> 16) == want &&
          (v3[2] >> 16) == want && (v3[3] >> 16) == want;
      if (ok) break;
    }
    {
      u16x4 s0 = {(ushort)v0[0], (ushort)v0[1], (ushort)v0[2], (ushort)v0[3]};
      u16x4 s1 = {(ushort)v1[0], (ushort)v1[1], (ushort)v1[2], (ushort)v1[3]};
      u16x4 s2 = {(ushort)v2[0], (ushort)v2[1], (ushort)v2[2], (ushort)v2[3]};
      u16x4 s3 = {(ushort)v3[0], (ushort)v3[1], (ushort)v3[2], (ushort)v3[3]};
      *(u16x4*)(hsm + (tid << 2))        = s0;
      *(u16x4*)(hsm + (tid << 2) + 2048) = s1;
      *(u16x4*)(hsm + (tid << 2) + 4096) = s2;
      *(u16x4*)(hsm + (tid << 2) + 6144) = s3;
    }
    __syncthreads();

    // ---- MFMA: z^T = U^T (A, regs) x h^T (B, LDS) ----
    const bf16x8* bb = ((const bf16x8*)hsm) + l;
    f32x4 acch = {0.f, 0.f, 0.f, 0.f};
    f32x4 accl = {0.f, 0.f, 0.f, 0.f};
#pragma unroll
    for (int ks = 0; ks < 16; ++ks) {
      const bf16x8 bfr = bb[ks * 64];
      acch = __builtin_amdgcn_mfma_f32_16x16x32_bf16(ufhi[ks], bfr, acch, 0, 0, 0);
      accl = __builtin_amdgcn_mfma_f32_16x16x32_bf16(uflo[ks], bfr, accl, 0, 0, 0);
    }

    const float zi = acch[0] + accl[0] + xzc[0];
    const float zf = acch[1] + accl[1] + xzc[1];
    const float zg = acch[2] + accl[2] + xzc[2];
    const float zo = acch[3] + accl[3] + xzc[3];
    const float iv = sigf(zi), fv = sigf(zf), gv = tanhff(zg), ov = sigf(zo);
    cst = fv * cst + iv * gv;
    const float hv = ov * tanhff(cst);

    lsm[loc] = (((uint)(t + 1)) << 16) | (uint)f2bf(hv);
    __syncthreads();

    // coalesced exchange commit
    if (tid < 128) {
      const u32x4 ov4 = *(const u32x4*)(lsm + (tid << 2));
      uint* wp = hfrag_u + wbuf + ((uint)s << 9) + (tid << 2);
      asm volatile("global_store_dwordx4 %0, %1, off sc0 sc1"
                   :: "v"(wp), "v"(ov4) : "memory");
    }
    h_seq[((size_t)beta * Tn + t) * Hn + hc] = f2bf(hv);   // bf16 h_seq

#pragma unroll
    for (int r = 0; r < 4; ++r) xzc[r] = xzn[r];
  }
}

// ---------------- K3: out = h_seq(bf16) @ Wd + bd ----------------
__global__ __launch_bounds__(256) void proj_out(
    const ushort* __restrict__ h_seq, const float* __restrict__ Wd,
    const float* __restrict__ bd, float* __restrict__ out)
{
  __shared__ float Wdt[10][516];
  for (int i = threadIdx.x; i < Hn * On; i += 256) {
    const int k = i / 10, o = i - k * 10;
    Wdt[o][k] = Wd[i];
  }
  __syncthreads();
  const int idx = blockIdx.x * 256 + threadIdx.x;
  const int row = idx / 10, o = idx - row * 10;
  const ushort* hp = h_seq + (size_t)row * Hn;
  const float* wp = &Wdt[o][0];
  float acc = bd[o];
#pragma unroll 2
  for (int k = 0; k < Hn; k += 8) {
    const u16x8 h8 = *(const u16x8*)(hp + k);
#pragma unroll
    for (int e = 0; e < 8; ++e)
      acc = fmaf(bf2f(h8[e]), wp[k + e], acc);
  }
  out[idx] = acc;
}

extern "C" void kernel_launch(void* const* d_in, const int* in_sizes, int n_in,
                              void* d_out, int out_size, void* d_ws, size_t ws_size,
                              hipStream_t stream)
{
  const float* x  = (const float*)d_in[0];
  const float* W  = (const float*)d_in[1];
  const float* U  = (const float*)d_in[2];
  const float* b  = (const float*)d_in[3];
  const float* Wd = (const float*)d_in[4];
  const float* bd = (const float*)d_in[5];
  float* out = (float*)d_out;

  // full layout (361 MB): xzT | hfrag | cnt | xhi | WThi | WTlo | h_seq(bf16)
  float* xzT    = (float*)d_ws;
  uint* hfrag_u = (uint*)(xzT + XZ_ELEMS);          // 65536 tagged uints
  uint* cnt     = hfrag_u + 65536;                  // 128 counters
  ushort* xhi   = (ushort*)(cnt + 128);
  ushort* WThi  = xhi + (size_t)32768 * KP;
  ushort* WTlo  = WThi + (size_t)G4n * KP;
  ushort* h_seq = WTlo + (size_t)G4n * KP;
  const size_t FULL_END = (size_t)((char*)(h_seq + HSEQ_ELEMS) - (char*)d_ws);

  if (ws_size >= FULL_END) {
    cvt_x<<<12800, 256, 0, stream>>>(x, xhi);
    cvt_w<<<800, 256, 0, stream>>>(W, WThi, WTlo);
    hipMemsetAsync(hfrag_u, 0, (65536 + 128) * sizeof(uint), stream);
    fused_lstm<<<256, 512, 0, stream>>>(xzT, U, h_seq, hfrag_u, cnt,
                                        WThi, WTlo, xhi, b, 1);
  } else {
    // fallback: compact layout, serial fp32 gemm, producers disabled
    h_seq = (ushort*)(cnt + 128);
    gemm_xz_f32<<<dim3(G4n / 64, Tn), 256, 0, stream>>>(x, W, b, xzT);
    hipMemsetAsync(hfrag_u, 0, (65536 + 128) * sizeof(uint), stream);
    fill_cnt<<<1, 128, 0, stream>>>(cnt);
    fused_lstm<<<256, 512, 0, stream>>>(xzT, U, h_seq, hfrag_u, cnt,
                                        (const ushort*)xzT, (const ushort*)xzT,
                                        (const ushort*)xzT, b, 0);
  }

  proj_out<<<(Bn * Tn * On) / 256, 256, 0, stream>>>(h_seq, Wd, bd, out);
}